// Round 7
// baseline (135.430 us; speedup 1.0000x reference)
//
#include <hip/hip_runtime.h>
#include <hip/hip_bf16.h>
#include <stdint.h>

#define T_STEPS 100
#define BATCH   256
#define HDIM    2048
#define FDIM    720
#define KP0     736                      // FDIM padded to 23*32
#define MROWS   (T_STEPS * BATCH)        // 25600

typedef __hip_bfloat16 bf16;
typedef float f32x4 __attribute__((ext_vector_type(4)));
typedef short bf16x8 __attribute__((ext_vector_type(8)));
typedef unsigned short u16x8 __attribute__((ext_vector_type(8)));

// Operator theorem (rounds 3-6, absmax 0.0): layers 1-2 L2-normalize currents
// => |c| <= 1; LIF v'=(v+c)/2 needs c>1 to reach threshold from v<1 => layers
// 1-2 never spike => goodness == 0. Only layer 0 is computed.

__device__ __forceinline__ void glds16(const bf16* g, bf16* l) {
    __builtin_amdgcn_global_load_lds(
        (const __attribute__((address_space(1))) void*)g,
        (__attribute__((address_space(3))) void*)l,
        16, 0, 0);
}

// ---------------- W0 fp32 [2048,720] -> bf16 [2048,736] zero-padded
__global__ __launch_bounds__(256)
void cvt_w0(const float* __restrict__ W, bf16* __restrict__ Wb) {
    int idx = blockIdx.x * 256 + threadIdx.x;
    int n = idx / KP0, k = idx % KP0;
    float w = (k < FDIM) ? W[(size_t)n * FDIM + k] : 0.0f;
    Wb[idx] = __float2bfloat16(w);
}

// ---------------- x fp32 [25600,720] -> bf16 [25600,736] padded, vectorized
__global__ __launch_bounds__(256)
void cvt_x(const float* __restrict__ x, bf16* __restrict__ xb) {
    int idx = blockIdx.x * 256 + threadIdx.x;       // over 25600*92
    int row = idx / 92, c8 = (idx % 92) * 8;
    bf16 tmp[8];
    if (c8 < FDIM) {
        const float* src = x + (size_t)row * FDIM + c8;
        float4 a = *reinterpret_cast<const float4*>(src);
        float4 b = *reinterpret_cast<const float4*>(src + 4);
        tmp[0] = __float2bfloat16(a.x); tmp[1] = __float2bfloat16(a.y);
        tmp[2] = __float2bfloat16(a.z); tmp[3] = __float2bfloat16(a.w);
        tmp[4] = __float2bfloat16(b.x); tmp[5] = __float2bfloat16(b.y);
        tmp[6] = __float2bfloat16(b.z); tmp[7] = __float2bfloat16(b.w);
    } else {
#pragma unroll
        for (int j = 0; j < 8; ++j) tmp[j] = __float2bfloat16(0.0f);
    }
    *reinterpret_cast<u16x8*>(xb + (size_t)row * KP0 + c8) =
        *reinterpret_cast<const u16x8*>(tmp);
}

// ---------------- fused layer-0: GEMM(tile per t) + LIF + goodness
// 256 blocks = 8 b-blocks x 32 h-blocks; tile 32(b) x 64(h); 8 waves:
// (mf 2) x (np 2) x (kh 2 K-split). B in regs; A in 3-buffer LDS pipeline
// (96-slot padded rows, XOR bank swizzle, depth-2 prefetch, counted vmcnt).
#define A_SLOTS 3072                     // 32 rows x 96 slots (16B each)
#define A_ELE   (A_SLOTS * 8)            // 24576 bf16
#define A_BYTES (A_ELE * 2)              // 49152
#define NBUF    3
#define RED_OFF (NBUF * A_BYTES)         // 147456
#define LDS_BYTES (RED_OFF + 16384)      // 163840 == full 160 KiB

__global__ __launch_bounds__(512, 1)
void fused_l0(const bf16* __restrict__ xb, const bf16* __restrict__ Wb,
              const float* __restrict__ bias, int* __restrict__ gbuf) {
    extern __shared__ char smem[];
    bf16*  Ab0 = (bf16*)smem;                        // 3 x 24576 bf16
    float* red = (float*)(smem + RED_OFF);           // 2 x 2048 f32 (parity)

    const int tid  = threadIdx.x;
    const int lane = tid & 63, w = tid >> 6;
    const int mf = w & 1, np = (w >> 1) & 1, kh = w >> 2;
    const int fr = lane & 15, fq = lane >> 4;
    const int b0 = (blockIdx.x & 7) * 32;            // b-block -> XCD affinity
    const int n0 = (blockIdx.x >> 3) * 64;
    const int nst = kh ? 11 : 12;                    // K-split: 12 + 11 k-steps
    const int kb  = kh * 12;
    const int q   = fr & 7;

    // ---- B panel (W0) into registers
    bf16x8 bv[2][12];
    {
        const bf16* wb0 = Wb + (size_t)(n0 + np * 32 + fr) * KP0 + fq * 8;
#pragma unroll
        for (int kk = 0; kk < 12; ++kk)
            if (kk < nst) {
                bv[0][kk] = *(const bf16x8*)(wb0 + (kb + kk) * 32);
                bv[1][kk] = *(const bf16x8*)(wb0 + (size_t)16 * KP0 + (kb + kk) * 32);
            }
    }
    const float bias_s = bias[n0 + np * 32 + kh * 16 + fr];

    f32x4 acc0 = {}, acc1 = {};
    float v[4]   = {0.f, 0.f, 0.f, 0.f};
    int   cnt[4] = {0, 0, 0, 0};

    // ---- A staging: 3072 slots of 16B; LDS rows padded to 96 slots.
    // Slot si of row r holds global granule g = si ^ (r&7) (involution);
    // si with g >= 92 are dummy (never read). Uniform 6 loads/thread.
#define STAGE(T, P) do {                                                      \
        const size_t be_ = ((size_t)(T) * BATCH + b0) * KP0;                  \
        _Pragma("unroll")                                                     \
        for (int r_ = 0; r_ < 6; ++r_) {                                      \
            int s_ = r_ * 512 + tid;                                          \
            int row_ = s_ / 96, si_ = s_ - row_ * 96;                         \
            int g_ = si_ ^ (row_ & 7);                                        \
            const bf16* src_ = xb + be_ + (size_t)row_ * KP0 +                \
                               ((g_ < 92) ? g_ : 0) * 8;                      \
            glds16(src_, Ab0 + (P) * A_ELE + s_ * 8);                         \
        }                                                                     \
    } while (0)

    STAGE(0, 0);
    STAGE(1, 1);
    asm volatile("s_waitcnt vmcnt(6)" ::: "memory");   // stage(0) landed
    __builtin_amdgcn_s_barrier();

    const int rowoff = (mf * 16 + fr) * 768;           // LDS row = 768 elems
    int pr = 0;
#pragma unroll 1
    for (int t = 0; t < T_STEPS; ++t) {
        int ps = pr + 2; if (ps >= NBUF) ps -= NBUF;
        if (t + 2 < T_STEPS) STAGE(t + 2, ps);         // depth-2 prefetch

        const bf16* Ab = Ab0 + pr * A_ELE;
#pragma unroll
        for (int kk = 0; kk < 12; ++kk)
            if (kk < nst) {
                int g = (kb + kk) * 4 + fq;            // granule 0..91
                int slot = g ^ q;                      // bank-perm swizzle
                bf16x8 av = *(const bf16x8*)(Ab + rowoff + slot * 8);
                acc0 = __builtin_amdgcn_mfma_f32_16x16x32_bf16(av, bv[0][kk], acc0, 0, 0, 0);
                acc1 = __builtin_amdgcn_mfma_f32_16x16x32_bf16(av, bv[1][kk], acc1, 0, 0, 0);
            }

        // ---- K-split pair exchange (wave w <-> w^4), counted-vmcnt barrier
        const int par = t & 1;
        *(f32x4*)&red[par * 2048 + tid * 4] = kh ? acc0 : acc1;
        if (t < T_STEPS - 2)
            asm volatile("s_waitcnt vmcnt(6) lgkmcnt(0)" ::: "memory");
        else
            asm volatile("s_waitcnt vmcnt(0) lgkmcnt(0)" ::: "memory");
        __builtin_amdgcn_s_barrier();
        __builtin_amdgcn_sched_barrier(0);

        f32x4 oth  = *(const f32x4*)&red[par * 2048 + (tid ^ 256) * 4];
        f32x4 mine = kh ? acc1 : acc0;
#pragma unroll
        for (int j = 0; j < 4; ++j) {
            float c = mine[j] + oth[j] + bias_s;
            v[j] = 0.5f * (v[j] + c);
            if (v[j] >= 1.0f) { cnt[j] += 1; v[j] = 0.0f; }
        }
        acc0 = (f32x4){}; acc1 = (f32x4){};
        pr = pr + 1; if (pr >= NBUF) pr -= NBUF;
    }
#undef STAGE

    // ---- exact integer goodness (reuse red area as int scratch)
    __syncthreads();
    int* gred = (int*)red;
    if (tid < 32) gred[tid] = 0;
    __syncthreads();
#pragma unroll
    for (int j = 0; j < 4; ++j)
        atomicAdd(&gred[mf * 16 + fq * 4 + j], cnt[j] * cnt[j]);
    __syncthreads();
    if (tid < 32) atomicAdd(&gbuf[b0 + tid], gred[tid]);
}

// ---------------- out[0:256] = gbuf*scale; out[256:768] = 0 (theorem)
__global__ __launch_bounds__(256)
void finalize(const int* __restrict__ gbuf, float* __restrict__ out) {
    int i = blockIdx.x * 256 + threadIdx.x;   // 0..767
    out[i] = (i < BATCH)
        ? (float)gbuf[i] * (1.0f / ((float)HDIM * 10000.0f))
        : 0.0f;
}

extern "C" void kernel_launch(void* const* d_in, const int* in_sizes, int n_in,
                              void* d_out, int out_size, void* d_ws, size_t ws_size,
                              hipStream_t stream) {
    const float* x  = (const float*)d_in[0];
    const float* W0 = (const float*)d_in[1];
    const float* b0 = (const float*)d_in[2];
    float* out = (float*)d_out;

    (void)hipFuncSetAttribute((const void*)fused_l0,
                              hipFuncAttributeMaxDynamicSharedMemorySize,
                              LDS_BYTES);

    char* p = (char*)d_ws;
    bf16* xb   = (bf16*)p;  p += (size_t)MROWS * KP0 * 2;   // 37.7 MB
    bf16* W0b  = (bf16*)p;  p += (size_t)HDIM * KP0 * 2;    //  3.0 MB
    int*  gbuf = (int*)p;                                   //  1 KB

    hipMemsetAsync(gbuf, 0, BATCH * sizeof(int), stream);
    cvt_w0<<<HDIM * KP0 / 256, 256, 0, stream>>>(W0, W0b);
    cvt_x<<<MROWS * 92 / 256, 256, 0, stream>>>(x, xb);

    fused_l0<<<256, 512, LDS_BYTES, stream>>>(xb, W0b, b0, gbuf);

    finalize<<<3, 256, 0, stream>>>(gbuf, out);
}